// Round 1
// baseline (898.398 us; speedup 1.0000x reference)
//
#include <hip/hip_runtime.h>
#include <hip/hip_bf16.h>

// Problem geometry (fixed by reference):
//   x: (2, 32, 96,96,96) fp32; W: (1024,1024) fp32 [o][k]; bias: (1024,)
//   P=4 -> T=64, Q = 24^3 = 13824, spatial s = t*Q + q
//   GEMM: M=55296 (b,g,q), K=1024 (k=j*32+c), N=1024 (o)
//   A[m,k] = x[b][c][t_src*Q + q],  t_src = (32g + j + 48) & 63  (j = k>>5, c = k&31)
//   out[b][o&31][tt*Q + q] = Y[m,o] + bias[o],  tt = (32g + (o>>5) + 48) & 63

#define NSPAT 884736   // 96^3
#define QQ    13824    // 24^3

typedef __attribute__((ext_vector_type(4))) float f32x4;
typedef __attribute__((ext_vector_type(8))) short bf16x8;

__device__ __forceinline__ short f2bf(float f) {
  // round-to-nearest-even fp32 -> bf16 (no NaN handling needed: inputs are finite)
  unsigned u = __builtin_bit_cast(unsigned, f);
  u += 0x7fff + ((u >> 16) & 1);
  return (short)(u >> 16);
}

__global__ __launch_bounds__(256, 2)
void swin_gemm(const float* __restrict__ x, const float* __restrict__ Wm,
               const float* __restrict__ bias, float* __restrict__ out) {
  const int bid = blockIdx.x;
  const int nt  = bid & 7;     // n-tile: 8 tiles of 128 over N=1024
  const int mt  = bid >> 3;    // m-tile: 432 tiles of 128 over M=55296
  const int seg = mt / 108;    // (b,g) segment; Q/128 = 108 tiles per segment
  const int q0  = (mt - seg * 108) * 128;
  const int bb  = seg >> 1;
  const int g   = seg & 1;

  const int tid  = threadIdx.x;
  const int wv   = tid >> 6;
  const int wr   = wv >> 1;    // wave row (m): 0..1 -> 64 rows each
  const int wc   = wv & 1;     // wave col (n)
  const int lane = tid & 63;
  const int lm   = lane & 15;  // A row / B row / D col within 16-tile
  const int quad = lane >> 4;  // 0..3: k-octet select, D row group

  const int n0 = nt * 128 + wc * 64;

  // A offsets (floats) rel. to x + bb*32*NSPAT + t_src*QQ:
  //   frag i, elem t: (quad*8+t)*NSPAT + q0 + wr*64 + i*16 + lm
  int aoff[4];
#pragma unroll
  for (int i = 0; i < 4; i++)
    aoff[i] = (quad * 8) * NSPAT + q0 + wr * 64 + i * 16 + lm;

  // W row pointers: row (n0 + j*16 + lm), col base quad*8 (kc*32 added in-loop)
  const float* wptr[4];
#pragma unroll
  for (int j = 0; j < 4; j++)
    wptr[j] = Wm + (size_t)(n0 + j * 16 + lm) * 1024 + quad * 8;

  f32x4 acc[4][4];
#pragma unroll
  for (int i = 0; i < 4; i++)
#pragma unroll
    for (int j = 0; j < 4; j++) {
      f32x4 z = {0.f, 0.f, 0.f, 0.f};
      acc[i][j] = z;
    }

  const float* xb = x + (size_t)bb * 32 * NSPAT;

  for (int kc = 0; kc < 32; kc++) {
    const int t_src = ((g << 5) + kc + 48) & 63;  // uniform per chunk
    const float* xs = xb + (size_t)t_src * QQ;

    bf16x8 af[4];
#pragma unroll
    for (int i = 0; i < 4; i++) {
      float v[8];
#pragma unroll
      for (int t = 0; t < 8; t++)
        v[t] = xs[aoff[i] + t * NSPAT];
      bf16x8 f;
#pragma unroll
      for (int t = 0; t < 8; t++) f[t] = f2bf(v[t]);
      af[i] = f;
    }

    bf16x8 bfr[4];
#pragma unroll
    for (int j = 0; j < 4; j++) {
      const float* wp = wptr[j] + kc * 32;
      const f32x4 w0 = *(const f32x4*)(wp);
      const f32x4 w1 = *(const f32x4*)(wp + 4);
      bf16x8 f;
#pragma unroll
      for (int t = 0; t < 4; t++) { f[t] = f2bf(w0[t]); f[t + 4] = f2bf(w1[t]); }
      bfr[j] = f;
    }

#pragma unroll
    for (int i = 0; i < 4; i++)
#pragma unroll
      for (int j = 0; j < 4; j++)
        acc[i][j] = __builtin_amdgcn_mfma_f32_16x16x32_bf16(af[i], bfr[j], acc[i][j], 0, 0, 0);
  }

  // Epilogue: D[row = quad*4 + r][col = lm]; row -> q (contiguous), col -> o
  float* ob = out + (size_t)bb * 32 * NSPAT;
#pragma unroll
  for (int j = 0; j < 4; j++) {
    const int o  = n0 + j * 16 + lm;
    const float bv = bias[o];
    const int so = o >> 5;
    const int cc = o & 31;
    const int tt = ((g << 5) + so + 48) & 63;
    float* orow = ob + (size_t)cc * NSPAT + (size_t)tt * QQ + q0;
#pragma unroll
    for (int i = 0; i < 4; i++) {
      const int mb = wr * 64 + i * 16 + quad * 4;
      f32x4 v = acc[i][j];
      v += bv;
      *(f32x4*)(orow + mb) = v;  // 16B-aligned: all terms multiples of 4 floats
    }
  }
}

extern "C" void kernel_launch(void* const* d_in, const int* in_sizes, int n_in,
                              void* d_out, int out_size, void* d_ws, size_t ws_size,
                              hipStream_t stream) {
  const float* x    = (const float*)d_in[0];
  const float* Wm   = (const float*)d_in[1];
  const float* bias = (const float*)d_in[2];
  float* out        = (float*)d_out;
  // grid = 432 m-tiles * 8 n-tiles; n fastest so sibling n-tiles (sharing A) are
  // temporally adjacent -> L3 catches the x re-reads
  swin_gemm<<<dim3(432 * 8), dim3(256), 0, stream>>>(x, Wm, bias, out);
}